// Round 7
// baseline (11958.995 us; speedup 1.0000x reference)
//
#include <hip/hip_runtime.h>
#include <hip/hip_bf16.h>

typedef __bf16 bf16x8 __attribute__((ext_vector_type(8)));
typedef float  f32x4  __attribute__((ext_vector_type(4)));
typedef unsigned long long ull;

#define Bq 64
#define Sq 512
#define Iq 512
#define Hq 1024
#define TSTEPS 511
#define MB 32          // batches per group (2 groups x 64 blocks = 128 CUs)
#define NCOLS 16       // h-columns per block
#define SHq (Sq*Hq)
#define TAGM 0x0001000100010001ull

__device__ inline unsigned short f2bf(float f){ return __builtin_bit_cast(unsigned short, (__bf16)f); }

// swizzled LDS byte addresses (break the 2048B/1024B row-stride bank conflict)
__device__ inline unsigned ah_addr(unsigned row, unsigned k){ return ((row<<11) + (k<<1)) ^ ((row&7)<<4); }
__device__ inline unsigned ax_addr(unsigned row, unsigned k){ return ((row<<10) + (k<<1)) ^ ((row&7)<<4); }

__device__ inline bf16x8 load_wfrag(const float* p){
  float4 a = *(const float4*)p;
  float4 b = *(const float4*)(p+4);
  bf16x8 w;
  w[0]=(__bf16)a.x; w[1]=(__bf16)a.y; w[2]=(__bf16)a.z; w[3]=(__bf16)a.w;
  w[4]=(__bf16)b.x; w[5]=(__bf16)b.y; w[6]=(__bf16)b.z; w[7]=(__bf16)b.w;
  return w;
}

// Tag protocol (r5): h^s lives in buffer s&1; every stored bf16's LSB =
// (s>>1)&1. kernel_launch memsets both buffers to 0xFF (stale for t=0/1;
// erases replay leftovers and the 0xAA ws-poison).
// Structure (r6, reshaped): 8-way K-split, WAVE-PRIVATE LDS slices (wave w
// owns h-cols [w*128,+128), x-cols [w*64,+64): stages+polls+MFMAs them with
// no block barrier). Cross-wave combine via ds_add_f32 into double-buffered
// accumulators; ONE __syncthreads per step; zero-on-read (zeros of step t
// ordered before step t+2 adds by S3(t+1)).
__global__ __launch_bounds__(512, 1) void gru_kernel(
    const float* __restrict__ x, const float* __restrict__ h0,
    const float* __restrict__ w_ir, const float* __restrict__ w_iz, const float* __restrict__ w_in_,
    const float* __restrict__ b_ir, const float* __restrict__ b_iz, const float* __restrict__ b_in_,
    const float* __restrict__ w_hr, const float* __restrict__ w_hz, const float* __restrict__ w_hn,
    const float* __restrict__ b_hr, const float* __restrict__ b_hz, const float* __restrict__ b_hn,
    float* __restrict__ out, void* ws)
{
  __shared__ unsigned short Ah[MB*Hq];   // 64 KB, swizzled, wave-sliced by cols
  __shared__ unsigned short Ax[MB*Iq];   // 32 KB, swizzled, wave-sliced by cols
  __shared__ float Pd[2][4][MB*NCOLS];   // 16 KB ds_add accumulators [buf][gate][32x16^swz]
  __shared__ float biasR[NCOLS], biasZ[NCOLS], biasNX[NCOLS], biasNH[NCOLS];

  const unsigned tid    = threadIdx.x;
  const unsigned bid    = blockIdx.x;
  const unsigned g      = bid & 1;        // batch group (64 blocks each, all 8 XCDs)
  const unsigned colbase= (bid >> 1) * NCOLS;
  const unsigned lane   = tid & 63;
  const unsigned w      = tid >> 6;       // wave = K-eighth
  const unsigned l15    = lane & 15;
  const unsigned l4     = lane >> 4;

  unsigned short* hb0 = (unsigned short*)ws;          // ping-pong tagged h buffers
  unsigned short* hb1 = hb0 + Bq*Hq;

  // ---- init: Pd zeros + biases ----
  for (unsigned i = tid; i < 2*4*MB*NCOLS; i += 512) (&Pd[0][0][0])[i] = 0.f;
  if (tid < NCOLS) {
    unsigned c = colbase + tid;
    biasR[tid]  = b_ir[c] + b_hr[c];
    biasZ[tid]  = b_iz[c] + b_hz[c];
    biasNX[tid] = b_in_[c];
    biasNH[tid] = b_hn[c];
  }

  // ---- reduce role: each thread owns (row,col) forever; hold in REGISTER ----
  const unsigned rrow = tid >> 4, rcol = tid & 15;     // 32 rows x 16 cols = 512
  float hold;
  {
    unsigned b = g*MB + rrow, hcol = colbase + rcol;
    hold = h0[(size_t)b*Hq + hcol];
    out[(size_t)b*SHq + hcol] = hold;
    unsigned short u = (unsigned short)(f2bf(hold) & ~1u);   // tag 0
    __hip_atomic_store(hb0 + (size_t)b*Hq + hcol, u,
                       __ATOMIC_RELAXED, __HIP_MEMORY_SCOPE_AGENT);
  }

  // ---- stationary weights: 18 frags = 72 VGPR/wave (resident, no remat) ----
  // B-frag (16x16x32): col = lane&15, k = (lane>>4)*8 + [0..7]
  const unsigned hcf = colbase + l15;
  bf16x8 wRX[2], wZX[2], wNX[2];   // x-parts: ksteps w*2+j (K=512/8)
  bf16x8 wRH[4], wZH[4], wNH[4];   // h-parts: ksteps w*4+j (K=1024/8)
  #pragma unroll
  for (int j = 0; j < 2; ++j) {
    unsigned off = (w*2 + j)*32 + l4*8;
    wRX[j] = load_wfrag(w_ir  + (size_t)hcf*Iq + off);
    wZX[j] = load_wfrag(w_iz  + (size_t)hcf*Iq + off);
    wNX[j] = load_wfrag(w_in_ + (size_t)hcf*Iq + off);
  }
  #pragma unroll
  for (int j = 0; j < 4; ++j) {
    unsigned off = (w*4 + j)*32 + l4*8;
    wRH[j] = load_wfrag(w_hr + (size_t)hcf*Hq + off);
    wZH[j] = load_wfrag(w_hz + (size_t)hcf*Hq + off);
    wNH[j] = load_wfrag(w_hn + (size_t)hcf*Hq + off);
  }

  // ---- staging roles (within wave) ----
  const unsigned xch = lane & 15, xrb = lane >> 4;   // x: rows xrb+4i (i<8), 4 f32 @ w*64+xch*4
  const unsigned hch = lane & 31, hrb = lane >> 5;   // h: rows hrb+2i (i<16), ull @ w*128+hch*4

  // ---- x prefetch for t=0 (x[:,1]) ----
  float4 xpf[8];
  #pragma unroll
  for (int i = 0; i < 8; ++i) {
    unsigned r = xrb + 4*i;
    xpf[i] = *(const float4*)(x + ((size_t)(g*MB+r)*Sq + 1)*Iq + w*64 + xch*4);
  }

  __syncthreads();   // Pd zeros + biases visible

  for (int t = 0; t < TSTEPS; ++t) {
    const unsigned short* hs = (t & 1) ? hb1 : hb0;
    unsigned short*       hd = (t & 1) ? hb0 : hb1;
    const ull want = ((t >> 1) & 1) ? TAGM : 0ull;
    const unsigned tagd = ((t + 1) >> 1) & 1;
    float* pb = &Pd[t & 1][0][0];

    // ---- stage own x slice from prefetched regs (wave-private) ----
    #pragma unroll
    for (int i = 0; i < 8; ++i) {
      unsigned r = xrb + 4*i;
      float4 v = xpf[i];
      ull pv = (ull)f2bf(v.x) | ((ull)f2bf(v.y) << 16)
             | ((ull)f2bf(v.z) << 32) | ((ull)f2bf(v.w) << 48);
      *(ull*)((char*)Ax + ax_addr(r, w*64 + xch*4)) = pv;
    }

    // ---- poll own h slice (32 rows x 128 cols): 16x8B, retry stale w/ backoff ----
    ull hv[16];
    const unsigned short* hsg = hs + (size_t)(g*MB)*Hq + w*128;
    #pragma unroll
    for (int i = 0; i < 16; ++i)
      hv[i] = __hip_atomic_load((const ull*)(hsg + (size_t)(hrb + 2*i)*Hq) + hch,
                                __ATOMIC_RELAXED, __HIP_MEMORY_SCOPE_AGENT);
    for (;;) {
      unsigned stale = 0;
      #pragma unroll
      for (int i = 0; i < 16; ++i)
        if ((hv[i] & TAGM) != want) stale |= 1u << i;
      if (!stale) break;
      __builtin_amdgcn_s_sleep(1);
      #pragma unroll
      for (int i = 0; i < 16; ++i)
        if (stale & (1u << i))
          hv[i] = __hip_atomic_load((const ull*)(hsg + (size_t)(hrb + 2*i)*Hq) + hch,
                                    __ATOMIC_RELAXED, __HIP_MEMORY_SCOPE_AGENT);
    }

    // ---- x prefetch for t+2 (hidden under MFMA+reduce) ----
    {
      int tt = (t + 2 <= Sq - 1) ? (t + 2) : (Sq - 1);
      #pragma unroll
      for (int i = 0; i < 8; ++i) {
        unsigned r = xrb + 4*i;
        xpf[i] = *(const float4*)(x + ((size_t)(g*MB+r)*Sq + (size_t)tt)*Iq + w*64 + xch*4);
      }
    }

    // ---- h -> own Ah slice (wave-private; no barrier before MFMA) ----
    #pragma unroll
    for (int i = 0; i < 16; ++i)
      *(ull*)((char*)Ah + ah_addr(hrb + 2*i, w*128 + hch*4)) = hv[i];

    // ---- MFMAs: 36/wave over 2 row-tiles ----
    f32x4 accR0={0,0,0,0}, accZ0={0,0,0,0}, accNX0={0,0,0,0}, accNH0={0,0,0,0};
    f32x4 accR1={0,0,0,0}, accZ1={0,0,0,0}, accNX1={0,0,0,0}, accNH1={0,0,0,0};
    #pragma unroll
    for (int j = 0; j < 2; ++j) {
      unsigned k = (w*2 + j)*32 + l4*8;
      bf16x8 a0 = *(const bf16x8*)((char*)Ax + ax_addr(l15,      k));
      bf16x8 a1 = *(const bf16x8*)((char*)Ax + ax_addr(16 + l15, k));
      accR0  = __builtin_amdgcn_mfma_f32_16x16x32_bf16(a0, wRX[j], accR0, 0, 0, 0);
      accR1  = __builtin_amdgcn_mfma_f32_16x16x32_bf16(a1, wRX[j], accR1, 0, 0, 0);
      accZ0  = __builtin_amdgcn_mfma_f32_16x16x32_bf16(a0, wZX[j], accZ0, 0, 0, 0);
      accZ1  = __builtin_amdgcn_mfma_f32_16x16x32_bf16(a1, wZX[j], accZ1, 0, 0, 0);
      accNX0 = __builtin_amdgcn_mfma_f32_16x16x32_bf16(a0, wNX[j], accNX0, 0, 0, 0);
      accNX1 = __builtin_amdgcn_mfma_f32_16x16x32_bf16(a1, wNX[j], accNX1, 0, 0, 0);
    }
    #pragma unroll
    for (int j = 0; j < 4; ++j) {
      unsigned k = (w*4 + j)*32 + l4*8;
      bf16x8 a0 = *(const bf16x8*)((char*)Ah + ah_addr(l15,      k));
      bf16x8 a1 = *(const bf16x8*)((char*)Ah + ah_addr(16 + l15, k));
      accR0  = __builtin_amdgcn_mfma_f32_16x16x32_bf16(a0, wRH[j], accR0, 0, 0, 0);
      accR1  = __builtin_amdgcn_mfma_f32_16x16x32_bf16(a1, wRH[j], accR1, 0, 0, 0);
      accZ0  = __builtin_amdgcn_mfma_f32_16x16x32_bf16(a0, wZH[j], accZ0, 0, 0, 0);
      accZ1  = __builtin_amdgcn_mfma_f32_16x16x32_bf16(a1, wZH[j], accZ1, 0, 0, 0);
      accNH0 = __builtin_amdgcn_mfma_f32_16x16x32_bf16(a0, wNH[j], accNH0, 0, 0, 0);
      accNH1 = __builtin_amdgcn_mfma_f32_16x16x32_bf16(a1, wNH[j], accNH1, 0, 0, 0);
    }

    // ---- cross-wave combine: ds_add_f32; XOR (l4&1)<<4 -> 2-way banks only ----
    #pragma unroll
    for (int i = 0; i < 4; ++i) {
      unsigned i0 = (((l4*4 + i)*16 + l15) ^ ((l4 & 1) << 4));        // row-tile 0
      unsigned i1 = (((16 + l4*4 + i)*16 + l15) ^ ((l4 & 1) << 4));   // row-tile 1
      atomicAdd(pb        + i0, accR0[i]);  atomicAdd(pb        + i1, accR1[i]);
      atomicAdd(pb +  512 + i0, accZ0[i]);  atomicAdd(pb +  512 + i1, accZ1[i]);
      atomicAdd(pb + 1024 + i0, accNX0[i]); atomicAdd(pb + 1024 + i1, accNX1[i]);
      atomicAdd(pb + 1536 + i0, accNH0[i]); atomicAdd(pb + 1536 + i1, accNH1[i]);
    }
    __syncthreads();   // S3: the ONLY per-step barrier

    // ---- reduce + gates + stores: 512 threads, 1 output each ----
    {
      const unsigned idx = ((rrow*16 + rcol) ^ (((rrow >> 2) & 1) << 4));
      float pr  = pb[idx];         pb[idx]        = 0.f;
      float pz  = pb[512 + idx];   pb[512 + idx]  = 0.f;
      float pnx = pb[1024 + idx];  pb[1024 + idx] = 0.f;
      float pnh = pb[1536 + idx];  pb[1536 + idx] = 0.f;

      float r = 1.f/(1.f + __expf(-(pr + biasR[rcol])));
      float z = 1.f/(1.f + __expf(-(pz + biasZ[rcol])));
      float nin = pnx + biasNX[rcol] + r*(pnh + biasNH[rcol]);
      float e2 = __expf(2.f*nin);
      float n = 1.f - 2.f/(e2 + 1.f);             // tanh
      float hn = (1.f - z)*n + z*hold;
      hold = hn;

      const unsigned b = g*MB + rrow, hcol = colbase + rcol;
      unsigned short u = (unsigned short)((f2bf(hn) & ~1u) | tagd);
      __hip_atomic_store(hd + (size_t)b*Hq + hcol, u,
                         __ATOMIC_RELAXED, __HIP_MEMORY_SCOPE_AGENT);
      out[(size_t)b*SHq + (size_t)(t+1)*Hq + hcol] = hn;
      if (t == TSTEPS-1)
        out[(size_t)Bq*SHq + (size_t)b*Hq + hcol] = hn;
    }
    // no second barrier: next step's ds_adds target buffer (t+1)&1; this
    // buffer's zeros are ordered before any t+2 adds by S3(t+1).
  }
}

extern "C" void kernel_launch(void* const* d_in, const int* in_sizes, int n_in,
                              void* d_out, int out_size, void* d_ws, size_t ws_size,
                              hipStream_t stream) {
  const float* x     = (const float*)d_in[0];
  const float* h0    = (const float*)d_in[1];
  const float* w_ir  = (const float*)d_in[2];
  const float* w_iz  = (const float*)d_in[3];
  const float* w_in_ = (const float*)d_in[4];
  const float* b_ir  = (const float*)d_in[5];
  const float* b_iz  = (const float*)d_in[6];
  const float* b_in_ = (const float*)d_in[7];
  const float* w_hr  = (const float*)d_in[8];
  const float* w_hz  = (const float*)d_in[9];
  const float* w_hn  = (const float*)d_in[10];
  const float* b_hr  = (const float*)d_in[11];
  const float* b_hz  = (const float*)d_in[12];
  const float* b_hn  = (const float*)d_in[13];
  float* out = (float*)d_out;

  // Precondition both tagged h ping-pong buffers to ALL-STALE (0xFFFF: tag 1,
  // bf16 NaN) -- erases replay leftovers and the harness's 0xAA ws-poison.
  hipMemsetAsync(d_ws, 0xFF, (size_t)2 * Bq * Hq * sizeof(unsigned short), stream);

  void* args[] = { (void*)&x, (void*)&h0, (void*)&w_ir, (void*)&w_iz, (void*)&w_in_,
                   (void*)&b_ir, (void*)&b_iz, (void*)&b_in_, (void*)&w_hr, (void*)&w_hz,
                   (void*)&w_hn, (void*)&b_hr, (void*)&b_hz, (void*)&b_hn,
                   (void*)&out, (void*)&d_ws };
  hipLaunchCooperativeKernel((void*)gru_kernel, dim3(128), dim3(512), args, 0, stream);
}

// Round 8
// 2209.561 us; speedup vs baseline: 5.4124x; 5.4124x over previous
//
#include <hip/hip_runtime.h>
#include <hip/hip_bf16.h>

typedef __bf16 bf16x8 __attribute__((ext_vector_type(8)));
typedef float  f32x4  __attribute__((ext_vector_type(4)));
typedef unsigned long long ull;

#define Bq 64
#define Sq 512
#define Iq 512
#define Hq 1024
#define TSTEPS 511
#define MB 32          // batches per group (2 groups x 64 blocks = 128 CUs)
#define NCOLS 16       // h-columns per block
#define SHq (Sq*Hq)
#define TAGM 0x0001000100010001ull

__device__ inline unsigned short f2bf(float f){ return __builtin_bit_cast(unsigned short, (__bf16)f); }

// swizzled LDS byte address for Ah (break the 2048B row-stride bank conflict)
__device__ inline unsigned ah_addr(unsigned row, unsigned k){ return ((row<<11) + (k<<1)) ^ ((row&7)<<4); }

__device__ inline bf16x8 load_wfrag(const float* p){
  float4 a = *(const float4*)p;
  float4 b = *(const float4*)(p+4);
  bf16x8 w;
  w[0]=(__bf16)a.x; w[1]=(__bf16)a.y; w[2]=(__bf16)a.z; w[3]=(__bf16)a.w;
  w[4]=(__bf16)b.x; w[5]=(__bf16)b.y; w[6]=(__bf16)b.z; w[7]=(__bf16)b.w;
  return w;
}

// x A-fragments loaded DIRECTLY global->regs (wave-private; no LDS staging)
__device__ inline void xload(float4* xr, const float* x, unsigned brow, unsigned s,
                             unsigned w, unsigned l15, unsigned l4){
  #pragma unroll
  for (int j = 0; j < 2; ++j)
    #pragma unroll
    for (int tl = 0; tl < 2; ++tl) {
      const float* xp = x + ((size_t)(brow + tl*16 + l15)*Sq + (size_t)s)*Iq + (w*2+j)*32 + l4*8;
      xr[(j*2+tl)*2+0] = *(const float4*)xp;
      xr[(j*2+tl)*2+1] = *(const float4*)(xp+4);
    }
}

// Tag protocol (r5/r7): h^s lives in buffer s&1; every stored bf16's LSB =
// (s>>1)&1. kernel_launch memsets both buffers to 0xFF (stale for t=0/1;
// erases replay leftovers and the 0xAA ws-poison).
// r8 = r7 with ONE mechanism swapped (bisect): the cross-wave combine is
// per-wave P slots + plain ds_write_b128 / ds_read (NO fp LDS atomics --
// those lower to contended CAS loops), 2 barriers/step. x staging LDS
// eliminated (direct global->reg A-frags) to fit P in LDS.
__global__ __launch_bounds__(512, 1) void gru_kernel(
    const float* __restrict__ x, const float* __restrict__ h0,
    const float* __restrict__ w_ir, const float* __restrict__ w_iz, const float* __restrict__ w_in_,
    const float* __restrict__ b_ir, const float* __restrict__ b_iz, const float* __restrict__ b_in_,
    const float* __restrict__ w_hr, const float* __restrict__ w_hz, const float* __restrict__ w_hn,
    const float* __restrict__ b_hr, const float* __restrict__ b_hz, const float* __restrict__ b_hn,
    float* __restrict__ out, void* ws)
{
  __shared__ unsigned short Ah[MB*Hq];   // 64 KB, swizzled, wave-sliced by cols
  __shared__ float P[8*2048];            // 64 KB per-wave partial slots (8 KB/wave)
  __shared__ float biasR[NCOLS], biasZ[NCOLS], biasNX[NCOLS], biasNH[NCOLS];

  const unsigned tid    = threadIdx.x;
  const unsigned bid    = blockIdx.x;
  const unsigned g      = bid & 1;        // batch group (64 blocks each)
  const unsigned colbase= (bid >> 1) * NCOLS;
  const unsigned lane   = tid & 63;
  const unsigned w      = tid >> 6;       // wave = K-eighth
  const unsigned l15    = lane & 15;
  const unsigned l4     = lane >> 4;

  unsigned short* hb0 = (unsigned short*)ws;          // ping-pong tagged h buffers
  unsigned short* hb1 = hb0 + Bq*Hq;

  if (tid < NCOLS) {
    unsigned c = colbase + tid;
    biasR[tid]  = b_ir[c] + b_hr[c];
    biasZ[tid]  = b_iz[c] + b_hz[c];
    biasNX[tid] = b_in_[c];
    biasNH[tid] = b_hn[c];
  }

  // ---- reduce role: each thread owns (row,col) forever; hold in REGISTER ----
  const unsigned rrow = tid >> 4, rcol = tid & 15;     // 32 rows x 16 cols
  float hold;
  {
    unsigned b = g*MB + rrow, hcol = colbase + rcol;
    hold = h0[(size_t)b*Hq + hcol];
    out[(size_t)b*SHq + hcol] = hold;
    unsigned short u = (unsigned short)(f2bf(hold) & ~1u);   // tag 0
    __hip_atomic_store(hb0 + (size_t)b*Hq + hcol, u,
                       __ATOMIC_RELAXED, __HIP_MEMORY_SCOPE_AGENT);
  }

  // ---- stationary weights: 18 frags = 72 VGPR/wave (resident) ----
  // B-frag (16x16x32): col = lane&15, k = (lane>>4)*8 + [0..7]
  const unsigned hcf = colbase + l15;
  bf16x8 wRX[2], wZX[2], wNX[2];   // x-parts: ksteps w*2+j
  bf16x8 wRH[4], wZH[4], wNH[4];   // h-parts: ksteps w*4+j
  #pragma unroll
  for (int j = 0; j < 2; ++j) {
    unsigned off = (w*2 + j)*32 + l4*8;
    wRX[j] = load_wfrag(w_ir  + (size_t)hcf*Iq + off);
    wZX[j] = load_wfrag(w_iz  + (size_t)hcf*Iq + off);
    wNX[j] = load_wfrag(w_in_ + (size_t)hcf*Iq + off);
  }
  #pragma unroll
  for (int j = 0; j < 4; ++j) {
    unsigned off = (w*4 + j)*32 + l4*8;
    wRH[j] = load_wfrag(w_hr + (size_t)hcf*Hq + off);
    wZH[j] = load_wfrag(w_hz + (size_t)hcf*Hq + off);
    wNH[j] = load_wfrag(w_hn + (size_t)hcf*Hq + off);
  }

  // ---- h poll/stage role (within wave) ----
  const unsigned hch = lane & 31, hrb = lane >> 5;   // rows hrb+2i (i<16), ull @ w*128+hch*4

  // ---- x A-frag prefetch for t=0 (slab 1) ----
  float4 xr[8];
  xload(xr, x, g*MB, 1, w, l15, l4);

  for (int t = 0; t < TSTEPS; ++t) {
    const unsigned short* hs = (t & 1) ? hb1 : hb0;
    unsigned short*       hd = (t & 1) ? hb0 : hb1;
    const ull want = ((t >> 1) & 1) ? TAGM : 0ull;
    const unsigned tagd = ((t + 1) >> 1) & 1;

    // ---- convert this step's x A-frags (loads issued last iter) ----
    bf16x8 xa[4];
    #pragma unroll
    for (int u = 0; u < 4; ++u) {
      float4 a = xr[u*2], b = xr[u*2+1];
      bf16x8 v;
      v[0]=(__bf16)a.x; v[1]=(__bf16)a.y; v[2]=(__bf16)a.z; v[3]=(__bf16)a.w;
      v[4]=(__bf16)b.x; v[5]=(__bf16)b.y; v[6]=(__bf16)b.z; v[7]=(__bf16)b.w;
      xa[u] = v;
    }

    // ---- poll own h slice (32 rows x 128 cols): 16x8B, retry stale w/ backoff ----
    ull hv[16];
    const unsigned short* hsg = hs + (size_t)(g*MB)*Hq + w*128;
    #pragma unroll
    for (int i = 0; i < 16; ++i)
      hv[i] = __hip_atomic_load((const ull*)(hsg + (size_t)(hrb + 2*i)*Hq) + hch,
                                __ATOMIC_RELAXED, __HIP_MEMORY_SCOPE_AGENT);
    for (;;) {
      unsigned stale = 0;
      #pragma unroll
      for (int i = 0; i < 16; ++i)
        if ((hv[i] & TAGM) != want) stale |= 1u << i;
      if (!stale) break;
      __builtin_amdgcn_s_sleep(1);
      #pragma unroll
      for (int i = 0; i < 16; ++i)
        if (stale & (1u << i))
          hv[i] = __hip_atomic_load((const ull*)(hsg + (size_t)(hrb + 2*i)*Hq) + hch,
                                    __ATOMIC_RELAXED, __HIP_MEMORY_SCOPE_AGENT);
    }

    // ---- issue x A-frag prefetch for t+1 (hidden under MFMA+reduce) ----
    {
      int tt = (t + 2 <= Sq - 1) ? (t + 2) : (Sq - 1);
      xload(xr, x, g*MB, (unsigned)tt, w, l15, l4);
    }

    // ---- h -> own Ah slice (wave-private; no barrier before MFMA) ----
    #pragma unroll
    for (int i = 0; i < 16; ++i)
      *(ull*)((char*)Ah + ah_addr(hrb + 2*i, w*128 + hch*4)) = hv[i];

    // ---- MFMAs: 36/wave over 2 row-tiles ----
    f32x4 accR0={0,0,0,0}, accZ0={0,0,0,0}, accNX0={0,0,0,0}, accNH0={0,0,0,0};
    f32x4 accR1={0,0,0,0}, accZ1={0,0,0,0}, accNX1={0,0,0,0}, accNH1={0,0,0,0};
    #pragma unroll
    for (int j = 0; j < 2; ++j) {
      accR0  = __builtin_amdgcn_mfma_f32_16x16x32_bf16(xa[j*2+0], wRX[j], accR0, 0, 0, 0);
      accR1  = __builtin_amdgcn_mfma_f32_16x16x32_bf16(xa[j*2+1], wRX[j], accR1, 0, 0, 0);
      accZ0  = __builtin_amdgcn_mfma_f32_16x16x32_bf16(xa[j*2+0], wZX[j], accZ0, 0, 0, 0);
      accZ1  = __builtin_amdgcn_mfma_f32_16x16x32_bf16(xa[j*2+1], wZX[j], accZ1, 0, 0, 0);
      accNX0 = __builtin_amdgcn_mfma_f32_16x16x32_bf16(xa[j*2+0], wNX[j], accNX0, 0, 0, 0);
      accNX1 = __builtin_amdgcn_mfma_f32_16x16x32_bf16(xa[j*2+1], wNX[j], accNX1, 0, 0, 0);
    }
    #pragma unroll
    for (int j = 0; j < 4; ++j) {
      unsigned k = (w*4 + j)*32 + l4*8;
      bf16x8 a0 = *(const bf16x8*)((char*)Ah + ah_addr(l15,      k));
      bf16x8 a1 = *(const bf16x8*)((char*)Ah + ah_addr(16 + l15, k));
      accR0  = __builtin_amdgcn_mfma_f32_16x16x32_bf16(a0, wRH[j], accR0, 0, 0, 0);
      accR1  = __builtin_amdgcn_mfma_f32_16x16x32_bf16(a1, wRH[j], accR1, 0, 0, 0);
      accZ0  = __builtin_amdgcn_mfma_f32_16x16x32_bf16(a0, wZH[j], accZ0, 0, 0, 0);
      accZ1  = __builtin_amdgcn_mfma_f32_16x16x32_bf16(a1, wZH[j], accZ1, 0, 0, 0);
      accNH0 = __builtin_amdgcn_mfma_f32_16x16x32_bf16(a0, wNH[j], accNH0, 0, 0, 0);
      accNH1 = __builtin_amdgcn_mfma_f32_16x16x32_bf16(a1, wNH[j], accNH1, 0, 0, 0);
    }

    // ---- per-wave partial slots: plain ds_write_b128, XOR(w<<2) swizzle ----
    {
      float* pw = P + w*2048;
      const unsigned fo = (lane*4) ^ (w << 2);
      *(f32x4*)(pw +    0 + fo) = accR0;   *(f32x4*)(pw +  256 + fo) = accR1;
      *(f32x4*)(pw +  512 + fo) = accZ0;   *(f32x4*)(pw +  768 + fo) = accZ1;
      *(f32x4*)(pw + 1024 + fo) = accNX0;  *(f32x4*)(pw + 1280 + fo) = accNX1;
      *(f32x4*)(pw + 1536 + fo) = accNH0;  *(f32x4*)(pw + 1792 + fo) = accNH1;
    }
    __syncthreads();   // S3: partials visible

    // ---- reduce over 8 wave-slots + gates + stores: 512 threads, 1 output ----
    {
      const unsigned rt = rrow >> 4, rr = rrow & 15;
      const unsigned fw = ((rr >> 2)*16 + rcol)*4 + (rr & 3);
      float pr = 0.f, pz = 0.f, pnx = 0.f, pnh = 0.f;
      #pragma unroll
      for (int ww = 0; ww < 8; ++ww) {
        const float* pb = P + ww*2048;
        const unsigned fo = fw ^ (ww << 2);
        pr  += pb[rt*256 + fo];
        pz  += pb[512  + rt*256 + fo];
        pnx += pb[1024 + rt*256 + fo];
        pnh += pb[1536 + rt*256 + fo];
      }

      float r = 1.f/(1.f + __expf(-(pr + biasR[rcol])));
      float z = 1.f/(1.f + __expf(-(pz + biasZ[rcol])));
      float nin = pnx + biasNX[rcol] + r*(pnh + biasNH[rcol]);
      float e2 = __expf(2.f*nin);
      float n = 1.f - 2.f/(e2 + 1.f);             // tanh
      float hn = (1.f - z)*n + z*hold;
      hold = hn;

      const unsigned b = g*MB + rrow, hcol = colbase + rcol;
      unsigned short u = (unsigned short)((f2bf(hn) & ~1u) | tagd);
      __hip_atomic_store(hd + (size_t)b*Hq + hcol, u,
                         __ATOMIC_RELAXED, __HIP_MEMORY_SCOPE_AGENT);
      out[(size_t)b*SHq + (size_t)(t+1)*Hq + hcol] = hn;
      if (t == TSTEPS-1)
        out[(size_t)Bq*SHq + (size_t)b*Hq + hcol] = hn;
    }
    __syncthreads();   // S4: P reads done before next step's P writes
  }
}

extern "C" void kernel_launch(void* const* d_in, const int* in_sizes, int n_in,
                              void* d_out, int out_size, void* d_ws, size_t ws_size,
                              hipStream_t stream) {
  const float* x     = (const float*)d_in[0];
  const float* h0    = (const float*)d_in[1];
  const float* w_ir  = (const float*)d_in[2];
  const float* w_iz  = (const float*)d_in[3];
  const float* w_in_ = (const float*)d_in[4];
  const float* b_ir  = (const float*)d_in[5];
  const float* b_iz  = (const float*)d_in[6];
  const float* b_in_ = (const float*)d_in[7];
  const float* w_hr  = (const float*)d_in[8];
  const float* w_hz  = (const float*)d_in[9];
  const float* w_hn  = (const float*)d_in[10];
  const float* b_hr  = (const float*)d_in[11];
  const float* b_hz  = (const float*)d_in[12];
  const float* b_hn  = (const float*)d_in[13];
  float* out = (float*)d_out;

  // Precondition both tagged h ping-pong buffers to ALL-STALE (0xFFFF: tag 1,
  // bf16 NaN) -- erases replay leftovers and the harness's 0xAA ws-poison.
  hipMemsetAsync(d_ws, 0xFF, (size_t)2 * Bq * Hq * sizeof(unsigned short), stream);

  void* args[] = { (void*)&x, (void*)&h0, (void*)&w_ir, (void*)&w_iz, (void*)&w_in_,
                   (void*)&b_ir, (void*)&b_iz, (void*)&b_in_, (void*)&w_hr, (void*)&w_hz,
                   (void*)&w_hn, (void*)&b_hr, (void*)&b_hz, (void*)&b_hn,
                   (void*)&out, (void*)&d_ws };
  hipLaunchCooperativeKernel((void*)gru_kernel, dim3(128), dim3(512), args, 0, stream);
}

// Round 10
// 1881.904 us; speedup vs baseline: 6.3547x; 1.1741x over previous
//
#include <hip/hip_runtime.h>
#include <hip/hip_bf16.h>

typedef __bf16 bf16x8 __attribute__((ext_vector_type(8)));
typedef float  f32x4  __attribute__((ext_vector_type(4)));
typedef unsigned long long ull;

#define Bq 64
#define Sq 512
#define Iq 512
#define Hq 1024
#define TSTEPS 511
#define MB 16          // batches per group (4 groups x 32 blocks = 128 CUs)
#define NCOLS 32       // h-columns per block
#define SHq (Sq*Hq)
#define TAGM 0x0001000100010001ull

__device__ inline unsigned short f2bf(float f){ return __builtin_bit_cast(unsigned short, (__bf16)f); }

// swizzled LDS byte address for Ah (break the 2048B row-stride bank conflict)
__device__ inline unsigned ah_addr(unsigned row, unsigned k){ return ((row<<11) + (k<<1)) ^ ((row&7)<<4); }

__device__ inline bf16x8 load_wfrag(const float* p){
  float4 a = *(const float4*)p;
  float4 b = *(const float4*)(p+4);
  bf16x8 w;
  w[0]=(__bf16)a.x; w[1]=(__bf16)a.y; w[2]=(__bf16)a.z; w[3]=(__bf16)a.w;
  w[4]=(__bf16)b.x; w[5]=(__bf16)b.y; w[6]=(__bf16)b.z; w[7]=(__bf16)b.w;
  return w;
}

// force-keep a weight frag resident: asm output is not rematerializable,
// so the allocator cannot re-load/re-convert it inside the loop (r5's
// VGPR=128 showed it otherwise does exactly that).
#define KEEP(v_) asm volatile("" : "+v"(v_))

// x A-fragments loaded DIRECTLY global->regs (wave-private; no LDS staging).
// Wave w covers x k-stripe [w*64, w*64+64) = ksteps w*2+j (j<2).
__device__ inline void xload(float4* xr, const float* x, unsigned brow, unsigned s,
                             unsigned w, unsigned l15, unsigned l4){
  #pragma unroll
  for (int j = 0; j < 2; ++j) {
    const float* xp = x + ((size_t)(brow + l15)*Sq + (size_t)s)*Iq + (w*2+j)*32 + l4*8;
    xr[j*2+0] = *(const float4*)xp;
    xr[j*2+1] = *(const float4*)(xp+4);
  }
}

// Tag protocol (r5): h^s lives in buffer s&1; every stored bf16's LSB =
// (s>>1)&1. kernel_launch memsets both buffers to 0xFF (stale for t=0/1;
// erases replay leftovers and the 0xAA ws-poison).
// Structure: 4 groups x 32 blocks (MB=16, NCOLS=32, 2 XCDs/group). 8-way
// K-split, wave-private Ah slices (wave w stages+MFMA-reads only cols
// [w*128,+128) -> no barrier before MFMA). Cross-wave combine: per-wave P
// slots, coalesced ds_write_b128, reduce reads offset gate*512+tid
// (contiguous, conflict-free). 2 barriers/step. NO fp LDS atomics (r7's
// 9x regression: CAS loops).
__global__ __launch_bounds__(512, 1) void gru_kernel(
    const float* __restrict__ x, const float* __restrict__ h0,
    const float* __restrict__ w_ir, const float* __restrict__ w_iz, const float* __restrict__ w_in_,
    const float* __restrict__ b_ir, const float* __restrict__ b_iz, const float* __restrict__ b_in_,
    const float* __restrict__ w_hr, const float* __restrict__ w_hz, const float* __restrict__ w_hn,
    const float* __restrict__ b_hr, const float* __restrict__ b_hz, const float* __restrict__ b_hn,
    float* __restrict__ out, void* ws)
{
  __shared__ unsigned short Ah[MB*Hq];   // 32 KB, swizzled, wave-sliced by cols
  __shared__ float P[8*2048];            // 64 KB per-wave partial slots (8 KB/wave)
  __shared__ float biasR[NCOLS], biasZ[NCOLS], biasNX[NCOLS], biasNH[NCOLS];

  const unsigned tid    = threadIdx.x;
  const unsigned bid    = blockIdx.x;
  const unsigned g      = bid & 3;        // batch group: 32 blocks on 2 XCDs
  const unsigned colbase= (bid >> 2) * NCOLS;
  const unsigned lane   = tid & 63;
  const unsigned w      = tid >> 6;       // wave = K-eighth
  const unsigned l15    = lane & 15;
  const unsigned l4     = lane >> 4;

  unsigned short* hb0 = (unsigned short*)ws;          // ping-pong tagged h buffers
  unsigned short* hb1 = hb0 + Bq*Hq;

  if (tid < NCOLS) {
    unsigned c = colbase + tid;
    biasR[tid]  = b_ir[c] + b_hr[c];
    biasZ[tid]  = b_iz[c] + b_hz[c];
    biasNX[tid] = b_in_[c];
    biasNH[tid] = b_hn[c];
  }

  // ---- reduce role: permuted 1:1 (row,col) ownership derived from the
  //      P slot layout so reduce reads are CONTIGUOUS (offset = gate*512+tid).
  const unsigned ctr = tid >> 8, Lr = (tid >> 2) & 63, ir = tid & 3;
  const unsigned rrow = ((Lr >> 4) << 2) + ir;          // 0..15
  const unsigned rcol = ctr*16 + (Lr & 15);             // 0..31
  float hold;
  {
    unsigned b = g*MB + rrow, hcol = colbase + rcol;
    hold = h0[(size_t)b*Hq + hcol];
    out[(size_t)b*SHq + hcol] = hold;
    unsigned short u = (unsigned short)(f2bf(hold) & ~1u);   // tag 0
    __hip_atomic_store(hb0 + (size_t)b*Hq + hcol, u,
                       __ATOMIC_RELAXED, __HIP_MEMORY_SCOPE_AGENT);
  }

  // ---- stationary weights: 36 frags = 144 VGPR/wave, FORCED resident ----
  // B-frag (16x16x32): col = lane&15, k = (lane>>4)*8 + [0..7]
  bf16x8 wRX[2][2], wZX[2][2], wNX[2][2];   // [ct][j], ksteps w*2+j
  bf16x8 wRH[2][4], wZH[2][4], wNH[2][4];   // [ct][j], ksteps w*4+j
  #pragma unroll
  for (int ct = 0; ct < 2; ++ct) {
    const unsigned hcf = colbase + ct*16 + l15;
    #pragma unroll
    for (int j = 0; j < 2; ++j) {
      unsigned off = (w*2 + j)*32 + l4*8;
      wRX[ct][j] = load_wfrag(w_ir  + (size_t)hcf*Iq + off);
      wZX[ct][j] = load_wfrag(w_iz  + (size_t)hcf*Iq + off);
      wNX[ct][j] = load_wfrag(w_in_ + (size_t)hcf*Iq + off);
      KEEP(wRX[ct][j]); KEEP(wZX[ct][j]); KEEP(wNX[ct][j]);
    }
    #pragma unroll
    for (int j = 0; j < 4; ++j) {
      unsigned off = (w*4 + j)*32 + l4*8;
      wRH[ct][j] = load_wfrag(w_hr + (size_t)hcf*Hq + off);
      wZH[ct][j] = load_wfrag(w_hz + (size_t)hcf*Hq + off);
      wNH[ct][j] = load_wfrag(w_hn + (size_t)hcf*Hq + off);
      KEEP(wRH[ct][j]); KEEP(wZH[ct][j]); KEEP(wNH[ct][j]);
    }
  }

  // ---- h poll/stage role (within wave): own 128-col stripe, 16 rows ----
  const unsigned hch = lane & 31, hrb = lane >> 5;   // rows hrb+2i (i<8), ull @ w*128+hch*4

  // ---- x A-frag prefetch for t=0 (slab 1) ----
  float4 xr[4];
  xload(xr, x, g*MB, 1, w, l15, l4);

  for (int t = 0; t < TSTEPS; ++t) {
    const unsigned short* hs = (t & 1) ? hb1 : hb0;
    unsigned short*       hd = (t & 1) ? hb0 : hb1;
    const ull want = ((t >> 1) & 1) ? TAGM : 0ull;
    const unsigned tagd = ((t + 1) >> 1) & 1;

    // ---- convert this step's x A-frags (loads issued last iter) ----
    bf16x8 xa[2];
    #pragma unroll
    for (int j = 0; j < 2; ++j) {
      float4 a = xr[j*2], b = xr[j*2+1];
      bf16x8 v;
      v[0]=(__bf16)a.x; v[1]=(__bf16)a.y; v[2]=(__bf16)a.z; v[3]=(__bf16)a.w;
      v[4]=(__bf16)b.x; v[5]=(__bf16)b.y; v[6]=(__bf16)b.z; v[7]=(__bf16)b.w;
      xa[j] = v;
    }

    // ---- poll own h slice (16 rows x 128 cols): 8x8B, retry stale w/ backoff ----
    ull hv[8];
    const unsigned short* hsg = hs + (size_t)(g*MB)*Hq + w*128;
    #pragma unroll
    for (int i = 0; i < 8; ++i)
      hv[i] = __hip_atomic_load((const ull*)(hsg + (size_t)(hrb + 2*i)*Hq) + hch,
                                __ATOMIC_RELAXED, __HIP_MEMORY_SCOPE_AGENT);
    for (;;) {
      unsigned stale = 0;
      #pragma unroll
      for (int i = 0; i < 8; ++i)
        if ((hv[i] & TAGM) != want) stale |= 1u << i;
      if (!stale) break;
      __builtin_amdgcn_s_sleep(1);
      #pragma unroll
      for (int i = 0; i < 8; ++i)
        if (stale & (1u << i))
          hv[i] = __hip_atomic_load((const ull*)(hsg + (size_t)(hrb + 2*i)*Hq) + hch,
                                    __ATOMIC_RELAXED, __HIP_MEMORY_SCOPE_AGENT);
    }

    // ---- issue x A-frag prefetch for t+1's consume (hidden under MFMA+reduce) ----
    {
      int tt = (t + 2 <= Sq - 1) ? (t + 2) : (Sq - 1);
      xload(xr, x, g*MB, (unsigned)tt, w, l15, l4);
    }

    // ---- h -> own Ah stripe (fully wave-private: no barrier needed, ever) ----
    #pragma unroll
    for (int i = 0; i < 8; ++i)
      *(ull*)((char*)Ah + ah_addr(hrb + 2*i, w*128 + hch*4)) = hv[i];

    // ---- MFMAs: 36/wave (2 col-tiles x {x:2 + h:4 ksteps} x 3 gates) ----
    f32x4 accR[2]={{0,0,0,0},{0,0,0,0}}, accZ[2]={{0,0,0,0},{0,0,0,0}};
    f32x4 accNX[2]={{0,0,0,0},{0,0,0,0}}, accNH[2]={{0,0,0,0},{0,0,0,0}};
    #pragma unroll
    for (int j = 0; j < 2; ++j)
      #pragma unroll
      for (int ct = 0; ct < 2; ++ct) {
        accR[ct]  = __builtin_amdgcn_mfma_f32_16x16x32_bf16(xa[j], wRX[ct][j], accR[ct], 0, 0, 0);
        accZ[ct]  = __builtin_amdgcn_mfma_f32_16x16x32_bf16(xa[j], wZX[ct][j], accZ[ct], 0, 0, 0);
        accNX[ct] = __builtin_amdgcn_mfma_f32_16x16x32_bf16(xa[j], wNX[ct][j], accNX[ct], 0, 0, 0);
      }
    #pragma unroll
    for (int j = 0; j < 4; ++j) {
      bf16x8 a = *(const bf16x8*)((char*)Ah + ah_addr(l15, (w*4 + j)*32 + l4*8));
      #pragma unroll
      for (int ct = 0; ct < 2; ++ct) {
        accR[ct]  = __builtin_amdgcn_mfma_f32_16x16x32_bf16(a, wRH[ct][j], accR[ct], 0, 0, 0);
        accZ[ct]  = __builtin_amdgcn_mfma_f32_16x16x32_bf16(a, wZH[ct][j], accZ[ct], 0, 0, 0);
        accNH[ct] = __builtin_amdgcn_mfma_f32_16x16x32_bf16(a, wNH[ct][j], accNH[ct], 0, 0, 0);
      }
    }

    // ---- per-wave partial slots: coalesced ds_write_b128 (conflict-free) ----
    {
      float* pw = P + w*2048 + lane*4;
      #pragma unroll
      for (int ct = 0; ct < 2; ++ct) {
        *(f32x4*)(pw +    0 + ct*256) = accR[ct];
        *(f32x4*)(pw +  512 + ct*256) = accZ[ct];
        *(f32x4*)(pw + 1024 + ct*256) = accNX[ct];
        *(f32x4*)(pw + 1536 + ct*256) = accNH[ct];
      }
    }
    __syncthreads();   // S3: partials visible

    // ---- reduce over 8 wave-slots (contiguous reads) + gates + stores ----
    {
      float pr = 0.f, pz = 0.f, pnx = 0.f, pnh = 0.f;
      #pragma unroll
      for (int ww = 0; ww < 8; ++ww) {
        const float* pb = P + ww*2048;
        pr  += pb[tid];
        pz  += pb[512  + tid];
        pnx += pb[1024 + tid];
        pnh += pb[1536 + tid];
      }

      float r = 1.f/(1.f + __expf(-(pr + biasR[rcol])));
      float z = 1.f/(1.f + __expf(-(pz + biasZ[rcol])));
      float nin = pnx + biasNX[rcol] + r*(pnh + biasNH[rcol]);
      float e2 = __expf(2.f*nin);
      float n = 1.f - 2.f/(e2 + 1.f);             // tanh
      float hn = (1.f - z)*n + z*hold;
      hold = hn;

      const unsigned b = g*MB + rrow, hcol = colbase + rcol;
      unsigned short u = (unsigned short)((f2bf(hn) & ~1u) | tagd);
      __hip_atomic_store(hd + (size_t)b*Hq + hcol, u,
                         __ATOMIC_RELAXED, __HIP_MEMORY_SCOPE_AGENT);
      out[(size_t)b*SHq + (size_t)(t+1)*Hq + hcol] = hn;
      if (t == TSTEPS-1)
        out[(size_t)Bq*SHq + (size_t)b*Hq + hcol] = hn;
    }
    __syncthreads();   // S4: P reads done before next step's P writes
  }
}

extern "C" void kernel_launch(void* const* d_in, const int* in_sizes, int n_in,
                              void* d_out, int out_size, void* d_ws, size_t ws_size,
                              hipStream_t stream) {
  const float* x     = (const float*)d_in[0];
  const float* h0    = (const float*)d_in[1];
  const float* w_ir  = (const float*)d_in[2];
  const float* w_iz  = (const float*)d_in[3];
  const float* w_in_ = (const float*)d_in[4];
  const float* b_ir  = (const float*)d_in[5];
  const float* b_iz  = (const float*)d_in[6];
  const float* b_in_ = (const float*)d_in[7];
  const float* w_hr  = (const float*)d_in[8];
  const float* w_hz  = (const float*)d_in[9];
  const float* w_hn  = (const float*)d_in[10];
  const float* b_hr  = (const float*)d_in[11];
  const float* b_hz  = (const float*)d_in[12];
  const float* b_hn  = (const float*)d_in[13];
  float* out = (float*)d_out;

  // Precondition both tagged h ping-pong buffers to ALL-STALE (0xFFFF: tag 1,
  // bf16 NaN) -- erases replay leftovers and the harness's 0xAA ws-poison.
  hipMemsetAsync(d_ws, 0xFF, (size_t)2 * Bq * Hq * sizeof(unsigned short), stream);

  void* args[] = { (void*)&x, (void*)&h0, (void*)&w_ir, (void*)&w_iz, (void*)&w_in_,
                   (void*)&b_ir, (void*)&b_iz, (void*)&b_in_, (void*)&w_hr, (void*)&w_hz,
                   (void*)&w_hn, (void*)&b_hr, (void*)&b_hz, (void*)&b_hn,
                   (void*)&out, (void*)&d_ws };
  hipLaunchCooperativeKernel((void*)gru_kernel, dim3(128), dim3(512), args, 0, stream);
}

// Round 11
// 1295.319 us; speedup vs baseline: 9.2325x; 1.4528x over previous
//
#include <hip/hip_runtime.h>
#include <hip/hip_bf16.h>

typedef __bf16 bf16x8 __attribute__((ext_vector_type(8)));
typedef float  f32x4  __attribute__((ext_vector_type(4)));
typedef unsigned long long ull;

#define Bq 64
#define Sq 512
#define Iq 512
#define Hq 1024
#define TSTEPS 511
#define MB 16          // batches per group (4 groups x 32 blocks = 128 CUs)
#define NCOLS 32       // h-columns per block
#define SHq (Sq*Hq)
#define TAGM 0x0001000100010001ull

__device__ inline unsigned short f2bf(float f){ return __builtin_bit_cast(unsigned short, (__bf16)f); }

// swizzled LDS byte addresses (break the 2048B/1024B row-stride bank conflict)
__device__ inline unsigned ah_addr(unsigned row, unsigned k){ return ((row<<11) + (k<<1)) ^ ((row&7)<<4); }
__device__ inline unsigned ax_addr(unsigned row, unsigned k){ return ((row<<10) + (k<<1)) ^ ((row&7)<<4); }

__device__ inline bf16x8 load_wfrag(const float* p){
  float4 a = *(const float4*)p;
  float4 b = *(const float4*)(p+4);
  bf16x8 w;
  w[0]=(__bf16)a.x; w[1]=(__bf16)a.y; w[2]=(__bf16)a.z; w[3]=(__bf16)a.w;
  w[4]=(__bf16)b.x; w[5]=(__bf16)b.y; w[6]=(__bf16)b.z; w[7]=(__bf16)b.w;
  return w;
}

// anti-remat tie (AGPR/VGPR residency hint; harmless if already resident)
#define KEEP(v_) asm volatile("" : "+v"(v_))

// Tag protocol (r5): h^s lives in buffer s&1; every stored bf16's LSB =
// (s>>1)&1. kernel_launch memsets both buffers to 0xFF (stale for t=0/1;
// erases replay leftovers and the 0xAA ws-poison).
// Structure: 4 groups x 32 blocks (MB=16, NCOLS=32). 8-way K-split with
// FULLY wave-private staging: wave w owns x-cols [w*64,+64) and h-cols
// [w*128,+128); it stages (COALESCED row-chunk loads -> LDS, r10's scattered
// direct loads were the regression: FETCH 169->232 MB), polls, and MFMAs its
// stripe with NO barrier. Cross-wave combine: per-wave P slots, coalesced
// writes, contiguous reduce reads (r10: conflicts 5.9e7->8.4e6). 2 barriers/
// step. NO fp LDS atomics (r7: CAS-loop 9x regression).
__global__ __launch_bounds__(512, 1) void gru_kernel(
    const float* __restrict__ x, const float* __restrict__ h0,
    const float* __restrict__ w_ir, const float* __restrict__ w_iz, const float* __restrict__ w_in_,
    const float* __restrict__ b_ir, const float* __restrict__ b_iz, const float* __restrict__ b_in_,
    const float* __restrict__ w_hr, const float* __restrict__ w_hz, const float* __restrict__ w_hn,
    const float* __restrict__ b_hr, const float* __restrict__ b_hz, const float* __restrict__ b_hn,
    float* __restrict__ out, void* ws)
{
  __shared__ unsigned short Ah[MB*Hq];   // 32 KB, swizzled, wave-sliced by k-stripe
  __shared__ unsigned short Ax[MB*Iq];   // 16 KB, swizzled, wave-sliced by k-stripe
  __shared__ float P[8*2048];            // 64 KB per-wave partial slots (8 KB/wave)
  __shared__ float biasR[NCOLS], biasZ[NCOLS], biasNX[NCOLS], biasNH[NCOLS];

  const unsigned tid    = threadIdx.x;
  const unsigned bid    = blockIdx.x;
  const unsigned g      = bid & 3;        // batch group: 32 blocks
  const unsigned colbase= (bid >> 2) * NCOLS;
  const unsigned lane   = tid & 63;
  const unsigned w      = tid >> 6;       // wave = K-eighth
  const unsigned l15    = lane & 15;
  const unsigned l4     = lane >> 4;

  unsigned short* hb0 = (unsigned short*)ws;          // ping-pong tagged h buffers
  unsigned short* hb1 = hb0 + Bq*Hq;

  if (tid < NCOLS) {
    unsigned c = colbase + tid;
    biasR[tid]  = b_ir[c] + b_hr[c];
    biasZ[tid]  = b_iz[c] + b_hz[c];
    biasNX[tid] = b_in_[c];
    biasNH[tid] = b_hn[c];
  }

  // ---- reduce role: permuted 1:1 (row,col) ownership so reduce reads are
  //      CONTIGUOUS (offset = gate*512 + tid); hold lives in a REGISTER.
  const unsigned ctr = tid >> 8, Lr = (tid >> 2) & 63, ir = tid & 3;
  const unsigned rrow = ((Lr >> 4) << 2) + ir;          // 0..15
  const unsigned rcol = ctr*16 + (Lr & 15);             // 0..31
  float hold;
  {
    unsigned b = g*MB + rrow, hcol = colbase + rcol;
    hold = h0[(size_t)b*Hq + hcol];
    out[(size_t)b*SHq + hcol] = hold;
    unsigned short u = (unsigned short)(f2bf(hold) & ~1u);   // tag 0
    __hip_atomic_store(hb0 + (size_t)b*Hq + hcol, u,
                       __ATOMIC_RELAXED, __HIP_MEMORY_SCOPE_AGENT);
  }

  // ---- stationary weights: 36 frags/wave (144 regs, VGPR/AGPR unified) ----
  // B-frag (16x16x32): col = lane&15, k = (lane>>4)*8 + [0..7]
  bf16x8 wRX[2][2], wZX[2][2], wNX[2][2];   // [ct][j], ksteps w*2+j
  bf16x8 wRH[2][4], wZH[2][4], wNH[2][4];   // [ct][j], ksteps w*4+j
  #pragma unroll
  for (int ct = 0; ct < 2; ++ct) {
    const unsigned hcf = colbase + ct*16 + l15;
    #pragma unroll
    for (int j = 0; j < 2; ++j) {
      unsigned off = (w*2 + j)*32 + l4*8;
      wRX[ct][j] = load_wfrag(w_ir  + (size_t)hcf*Iq + off);
      wZX[ct][j] = load_wfrag(w_iz  + (size_t)hcf*Iq + off);
      wNX[ct][j] = load_wfrag(w_in_ + (size_t)hcf*Iq + off);
      KEEP(wRX[ct][j]); KEEP(wZX[ct][j]); KEEP(wNX[ct][j]);
    }
    #pragma unroll
    for (int j = 0; j < 4; ++j) {
      unsigned off = (w*4 + j)*32 + l4*8;
      wRH[ct][j] = load_wfrag(w_hr + (size_t)hcf*Hq + off);
      wZH[ct][j] = load_wfrag(w_hz + (size_t)hcf*Hq + off);
      wNH[ct][j] = load_wfrag(w_hn + (size_t)hcf*Hq + off);
      KEEP(wRH[ct][j]); KEEP(wZH[ct][j]); KEEP(wNH[ct][j]);
    }
  }

  // ---- staging roles (within wave) ----
  const unsigned xcr = lane >> 4, xc16 = lane & 15;  // x: 4 rows/pass x 16B chunks (COALESCED 256B/row)
  const unsigned hch = lane & 31, hrb = lane >> 5;   // h: rows hrb+2i (i<8), ull @ w*128+hch*4

  // ---- x prefetch for t=0 (slab 1): wave-private k-stripe, coalesced ----
  float4 xpf[4];
  #pragma unroll
  for (int i = 0; i < 4; ++i)
    xpf[i] = *(const float4*)(x + ((size_t)(g*MB + xcr + 4*i)*Sq + 1)*Iq + w*64 + xc16*4);

  for (int t = 0; t < TSTEPS; ++t) {
    const unsigned short* hs = (t & 1) ? hb1 : hb0;
    unsigned short*       hd = (t & 1) ? hb0 : hb1;
    const ull want = ((t >> 1) & 1) ? TAGM : 0ull;
    const unsigned tagd = ((t + 1) >> 1) & 1;

    // ---- stage own x stripe from prefetched regs (wave-private, no barrier) ----
    #pragma unroll
    for (int i = 0; i < 4; ++i) {
      float4 v = xpf[i];
      ull pv = (ull)f2bf(v.x) | ((ull)f2bf(v.y) << 16)
             | ((ull)f2bf(v.z) << 32) | ((ull)f2bf(v.w) << 48);
      *(ull*)((char*)Ax + ax_addr(xcr + 4*i, w*64 + xc16*4)) = pv;
    }

    // ---- poll own h stripe (16 rows x 128 cols): 8x8B, retry stale w/ backoff ----
    ull hv[8];
    const unsigned short* hsg = hs + (size_t)(g*MB)*Hq + w*128;
    #pragma unroll
    for (int i = 0; i < 8; ++i)
      hv[i] = __hip_atomic_load((const ull*)(hsg + (size_t)(hrb + 2*i)*Hq) + hch,
                                __ATOMIC_RELAXED, __HIP_MEMORY_SCOPE_AGENT);
    for (;;) {
      unsigned stale = 0;
      #pragma unroll
      for (int i = 0; i < 8; ++i)
        if ((hv[i] & TAGM) != want) stale |= 1u << i;
      if (!stale) break;
      __builtin_amdgcn_s_sleep(1);
      #pragma unroll
      for (int i = 0; i < 8; ++i)
        if (stale & (1u << i))
          hv[i] = __hip_atomic_load((const ull*)(hsg + (size_t)(hrb + 2*i)*Hq) + hch,
                                    __ATOMIC_RELAXED, __HIP_MEMORY_SCOPE_AGENT);
    }

    // ---- x prefetch for t+2 (coalesced; hidden under MFMA+reduce) ----
    {
      int tt = (t + 2 <= Sq - 1) ? (t + 2) : (Sq - 1);
      #pragma unroll
      for (int i = 0; i < 4; ++i)
        xpf[i] = *(const float4*)(x + ((size_t)(g*MB + xcr + 4*i)*Sq + (size_t)tt)*Iq + w*64 + xc16*4);
    }

    // ---- h -> own Ah stripe (wave-private; no barrier before MFMA) ----
    #pragma unroll
    for (int i = 0; i < 8; ++i)
      *(ull*)((char*)Ah + ah_addr(hrb + 2*i, w*128 + hch*4)) = hv[i];

    // ---- MFMAs: 36/wave (2 col-tiles x {x:2 + h:4 ksteps} x 3 gates) ----
    f32x4 accR[2]={{0,0,0,0},{0,0,0,0}}, accZ[2]={{0,0,0,0},{0,0,0,0}};
    f32x4 accNX[2]={{0,0,0,0},{0,0,0,0}}, accNH[2]={{0,0,0,0},{0,0,0,0}};
    #pragma unroll
    for (int j = 0; j < 2; ++j) {
      bf16x8 a = *(const bf16x8*)((char*)Ax + ax_addr(l15, (w*2 + j)*32 + l4*8));
      #pragma unroll
      for (int ct = 0; ct < 2; ++ct) {
        accR[ct]  = __builtin_amdgcn_mfma_f32_16x16x32_bf16(a, wRX[ct][j], accR[ct], 0, 0, 0);
        accZ[ct]  = __builtin_amdgcn_mfma_f32_16x16x32_bf16(a, wZX[ct][j], accZ[ct], 0, 0, 0);
        accNX[ct] = __builtin_amdgcn_mfma_f32_16x16x32_bf16(a, wNX[ct][j], accNX[ct], 0, 0, 0);
      }
    }
    #pragma unroll
    for (int j = 0; j < 4; ++j) {
      bf16x8 a = *(const bf16x8*)((char*)Ah + ah_addr(l15, (w*4 + j)*32 + l4*8));
      #pragma unroll
      for (int ct = 0; ct < 2; ++ct) {
        accR[ct]  = __builtin_amdgcn_mfma_f32_16x16x32_bf16(a, wRH[ct][j], accR[ct], 0, 0, 0);
        accZ[ct]  = __builtin_amdgcn_mfma_f32_16x16x32_bf16(a, wZH[ct][j], accZ[ct], 0, 0, 0);
        accNH[ct] = __builtin_amdgcn_mfma_f32_16x16x32_bf16(a, wNH[ct][j], accNH[ct], 0, 0, 0);
      }
    }

    // ---- per-wave partial slots: coalesced ds_write_b128 (conflict-free) ----
    {
      float* pw = P + w*2048 + lane*4;
      #pragma unroll
      for (int ct = 0; ct < 2; ++ct) {
        *(f32x4*)(pw +    0 + ct*256) = accR[ct];
        *(f32x4*)(pw +  512 + ct*256) = accZ[ct];
        *(f32x4*)(pw + 1024 + ct*256) = accNX[ct];
        *(f32x4*)(pw + 1536 + ct*256) = accNH[ct];
      }
    }
    __syncthreads();   // S3: partials visible

    // ---- reduce over 8 wave-slots (contiguous reads) + gates + stores ----
    {
      float pr = 0.f, pz = 0.f, pnx = 0.f, pnh = 0.f;
      #pragma unroll
      for (int ww = 0; ww < 8; ++ww) {
        const float* pb = P + ww*2048;
        pr  += pb[tid];
        pz  += pb[512  + tid];
        pnx += pb[1024 + tid];
        pnh += pb[1536 + tid];
      }

      float r = 1.f/(1.f + __expf(-(pr + biasR[rcol])));
      float z = 1.f/(1.f + __expf(-(pz + biasZ[rcol])));
      float nin = pnx + biasNX[rcol] + r*(pnh + biasNH[rcol]);
      float e2 = __expf(2.f*nin);
      float n = 1.f - 2.f/(e2 + 1.f);             // tanh
      float hn = (1.f - z)*n + z*hold;
      hold = hn;

      const unsigned b = g*MB + rrow, hcol = colbase + rcol;
      unsigned short u = (unsigned short)((f2bf(hn) & ~1u) | tagd);
      __hip_atomic_store(hd + (size_t)b*Hq + hcol, u,
                         __ATOMIC_RELAXED, __HIP_MEMORY_SCOPE_AGENT);
      out[(size_t)b*SHq + (size_t)(t+1)*Hq + hcol] = hn;
      if (t == TSTEPS-1)
        out[(size_t)Bq*SHq + (size_t)b*Hq + hcol] = hn;
    }
    __syncthreads();   // S4: P reads done before next step's P writes
  }
}

extern "C" void kernel_launch(void* const* d_in, const int* in_sizes, int n_in,
                              void* d_out, int out_size, void* d_ws, size_t ws_size,
                              hipStream_t stream) {
  const float* x     = (const float*)d_in[0];
  const float* h0    = (const float*)d_in[1];
  const float* w_ir  = (const float*)d_in[2];
  const float* w_iz  = (const float*)d_in[3];
  const float* w_in_ = (const float*)d_in[4];
  const float* b_ir  = (const float*)d_in[5];
  const float* b_iz  = (const float*)d_in[6];
  const float* b_in_ = (const float*)d_in[7];
  const float* w_hr  = (const float*)d_in[8];
  const float* w_hz  = (const float*)d_in[9];
  const float* w_hn  = (const float*)d_in[10];
  const float* b_hr  = (const float*)d_in[11];
  const float* b_hz  = (const float*)d_in[12];
  const float* b_hn  = (const float*)d_in[13];
  float* out = (float*)d_out;

  // Precondition both tagged h ping-pong buffers to ALL-STALE (0xFFFF: tag 1,
  // bf16 NaN) -- erases replay leftovers and the harness's 0xAA ws-poison.
  hipMemsetAsync(d_ws, 0xFF, (size_t)2 * Bq * Hq * sizeof(unsigned short), stream);

  void* args[] = { (void*)&x, (void*)&h0, (void*)&w_ir, (void*)&w_iz, (void*)&w_in_,
                   (void*)&b_ir, (void*)&b_iz, (void*)&b_in_, (void*)&w_hr, (void*)&w_hz,
                   (void*)&w_hn, (void*)&b_hr, (void*)&b_hz, (void*)&b_hn,
                   (void*)&out, (void*)&d_ws };
  hipLaunchCooperativeKernel((void*)gru_kernel, dim3(128), dim3(512), args, 0, stream);
}